// Round 8
// baseline (126.840 us; speedup 1.0000x reference)
//
#include <hip/hip_runtime.h>
#include <hip/hip_fp16.h>

#define NQ 4096
#define NH 8
#define ND 32
#define NK 30720   // 16384+8192+4096+2048
#define LDSS 33    // padded LDS row stride (conflict-free)

// ---- Pre-pass: value fp32 -> fp16 into workspace (halves gather traffic) ----
__global__ __launch_bounds__(256) void cvt_kernel(const float* __restrict__ v,
                                                  uint4* __restrict__ o, int n8) {
    int i = blockIdx.x * blockDim.x + threadIdx.x;
    const float4* __restrict__ v4 = (const float4*)v;
    for (; i < n8; i += gridDim.x * blockDim.x) {
        const float4 f0 = v4[2 * i];
        const float4 f1 = v4[2 * i + 1];
        __half2 h0 = __floats2half2_rn(f0.x, f0.y);
        __half2 h1 = __floats2half2_rn(f0.z, f0.w);
        __half2 h2 = __floats2half2_rn(f1.x, f1.y);
        __half2 h3 = __floats2half2_rn(f1.z, f1.w);
        uint4 u;
        u.x = *reinterpret_cast<unsigned*>(&h0);
        u.y = *reinterpret_cast<unsigned*>(&h1);
        u.z = *reinterpret_cast<unsigned*>(&h2);
        u.w = *reinterpret_cast<unsigned*>(&h3);
        o[i] = u;
    }
}

__device__ __forceinline__ void load4(const uint2* __restrict__ vb2,
                                      const uint2* s_d, int jj, int cb,
                                      unsigned lane, unsigned* w,
                                      uint2* ra, uint2* rb) {
    #pragma unroll
    for (int u = 0; u < 4; ++u) {
        const uint2 d = s_d[(jj + u) * LDSS + cb];
        w[u]  = d.y;
        ra[u] = vb2[((d.x & 0xffffu) << 6) + lane];
        rb[u] = vb2[((d.x >> 16) << 6) + lane];
    }
}

__device__ __forceinline__ void consume4(const unsigned* w, const uint2* ra,
                                         const uint2* rb, float4& acc) {
    #pragma unroll
    for (int u = 0; u < 4; ++u) {
        const __half2 wh = *reinterpret_cast<const __half2*>(&w[u]);
        const float w1 = __low2float(wh);
        const float w2 = __high2float(wh);
        const float2 a0 = __half22float2(*(const __half2*)&ra[u].x);
        const float2 a1 = __half22float2(*(const __half2*)&ra[u].y);
        const float2 c0 = __half22float2(*(const __half2*)&rb[u].x);
        const float2 c1 = __half22float2(*(const __half2*)&rb[u].y);
        acc.x += w1 * a0.x + w2 * c0.x;
        acc.y += w1 * a0.y + w2 * c0.y;
        acc.z += w1 * a1.x + w2 * c1.x;
        acc.w += w1 * a1.y + w2 * c1.y;
    }
}

// Work partition (R5 winner): 8 groups = (batch, h-half), one per XCD; per-XCD
// distinct-line gather footprint = 3.93 MB fp16 (~L2-capacity-bounded, so deep
// issue cannot thrash like pre-partition R3/R4). Block: 8 queries x 4 heads.
// Phase 1: 1024 packed descriptors {k1|k2<<16, half2(w1,w2)} into LDS.
// Phase 2: depth-4 A/B pipelined gather. launch_bounds(256,6): VGPR cap 85 --
// R6's (256,8) cap of 64 caused scratch spill (WRITE_SIZE 196MB); spill-guard
// this round = WRITE_SIZE must stay ~16MB.
template <bool FP16>
__global__ __launch_bounds__(256, 6) void spd_kernel(
    const float* __restrict__ value,   // (bs, NK, H, D) fp32
    const __half* __restrict__ vh,     // same, fp16 (workspace), if FP16
    const float* __restrict__ loc,     // (bs, NQ, H, LV, P, 1)
    const float* __restrict__ wts,     // (bs, NQ, H, LV, P)
    float* __restrict__ out)           // (bs, NQ, H*D)
{
    const int tid = threadIdx.x;
    const int g  = blockIdx.x & 7;     // XCD id = group = b*2 + hh
    const int w  = blockIdx.x >> 3;    // [0,512) within group
    const int b  = g >> 1;
    const int hh = g & 1;              // which half of the 8 heads
    const int q0 = w << 3;             // first of 8 queries

    __shared__ uint2 s_d[32 * LDSS];   // [row=l*8+p][col=q*4+h4]

    // ---- Phase 1: descriptors for 8 queries x 4 heads x 32 taps ----
    const size_t base = ((size_t)(b * NQ + q0) * 8 + hh * 4) * 32;
    #pragma unroll
    for (int e = 0; e < 4; ++e) {
        const int ent = (e << 8) | tid;    // q(3b)|h4(2b)|l(2b)|p(3b)
        const size_t gidx = base + (size_t)(ent >> 7) * 256 + (ent & 127);
        const float x_loc = loc[gidx];
        const float wq    = wts[gidx];

        const int l   = (ent >> 3) & 3;
        const int L   = 16384 >> l;
        const int off = 32768 - (32768 >> l); // 0,16384,24576,28672

        const float x  = x_loc * (float)L - 1.0f;
        const float xf = floorf(x);
        const float lx = x - xf;
        const float hx = 1.0f - lx;
        const int   xl = (int)xf;
        const int   xh = xl + 1;

        const bool ok1 = (xl >= 0) && (xl < L);
        const bool ok2 = (xh >= 0) && (xh < L);
        int c1 = xl < 0 ? 0 : (xl > L - 1 ? L - 1 : xl);
        int c2 = xh < 0 ? 0 : (xh > L - 1 ? L - 1 : xh);
        const float w1 = ok1 ? wq * hx : 0.0f;
        const float w2 = ok2 ? wq * lx : 0.0f;

        const int li = (ent & 31) * LDSS + (ent >> 5);  // row=lp, col=q*4+h4
        __half2 wh = __floats2half2_rn(w1, w2);
        uint2 d;
        d.x = (unsigned)(off + c1) | ((unsigned)(off + c2) << 16);
        d.y = *reinterpret_cast<unsigned*>(&wh);
        s_d[li] = d;
    }
    __syncthreads();

    // ---- Phase 2: pipelined gather + accumulate ----
    const int qi = tid >> 5;                 // query within block [0,8)
    const int cb = tid >> 3;                 // LDS col = q*4+h4 [0,32)
    const int h  = (hh << 2) | ((tid >> 3) & 3);
    const int d4 = tid & 7;
    const unsigned lane = (unsigned)((h << 3) | d4);  // slice within key row

    float4 acc = make_float4(0.f, 0.f, 0.f, 0.f);

    if (FP16) {
        const uint2* __restrict__ vb2 =
            (const uint2*)(vh) + (size_t)b * (NK * 64);   // 64 uint2 per key

        unsigned wA[4], wB[4];
        uint2 aA[4], bA[4], aB[4], bB[4];

        load4(vb2, s_d, 0, cb, lane, wA, aA, bA);
        load4(vb2, s_d, 4, cb, lane, wB, aB, bB);
        #pragma unroll
        for (int jj = 8; jj < 32; jj += 8) {
            consume4(wA, aA, bA, acc);
            load4(vb2, s_d, jj, cb, lane, wA, aA, bA);
            consume4(wB, aB, bB, acc);
            load4(vb2, s_d, jj + 4, cb, lane, wB, aB, bB);
        }
        consume4(wA, aA, bA, acc);
        consume4(wB, aB, bB, acc);
    } else {
        const float4* __restrict__ vb4 =
            (const float4*)(value) + (size_t)b * (NK * 64); // 64 float4 per key
        #pragma unroll 16
        for (int j = 0; j < 32; ++j) {
            const uint2 d = s_d[j * LDSS + cb];
            const __half2 wh = *reinterpret_cast<const __half2*>(&d.y);
            const float w1 = __low2float(wh);
            const float w2 = __high2float(wh);
            const float4 a = vb4[(size_t)((d.x & 0xffffu) << 6) + lane];
            const float4 c = vb4[(size_t)((d.x >> 16) << 6) + lane];
            acc.x += w1 * a.x + w2 * c.x;
            acc.y += w1 * a.y + w2 * c.y;
            acc.z += w1 * a.z + w2 * c.z;
            acc.w += w1 * a.w + w2 * c.w;
        }
    }

    float4* __restrict__ o4 = (float4*)out;
    o4[(size_t)(b * NQ + q0 + qi) * 64 + lane] = acc;
}

extern "C" void kernel_launch(void* const* d_in, const int* in_sizes, int n_in,
                              void* d_out, int out_size, void* d_ws, size_t ws_size,
                              hipStream_t stream) {
    const float* value = (const float*)d_in[0];
    const float* loc   = (const float*)d_in[1];
    const float* wts   = (const float*)d_in[2];
    float* out = (float*)d_out;

    const int bs = 4;
    const int blocks = 8 * (NQ / 8);  // 8 groups x 512 = 4096
    const size_t need = (size_t)bs * NK * NH * ND * sizeof(__half);  // ~63 MB

    if (ws_size >= need) {
        const int n8 = bs * NK * NH * ND / 8;  // 8 floats per thread-iter
        cvt_kernel<<<2048, 256, 0, stream>>>(value, (uint4*)d_ws, n8);
        spd_kernel<true><<<blocks, 256, 0, stream>>>(value, (const __half*)d_ws,
                                                     loc, wts, out);
    } else {
        spd_kernel<false><<<blocks, 256, 0, stream>>>(value, nullptr,
                                                      loc, wts, out);
    }
}

// Round 9
// 86.848 us; speedup vs baseline: 1.4605x; 1.4605x over previous
//
#include <hip/hip_runtime.h>
#include <hip/hip_fp16.h>

#define NQ 4096
#define NH 8
#define ND 32
#define NK 30720   // 16384+8192+4096+2048
#define LDSS 33    // padded LDS row stride (conflict-free)

typedef __attribute__((address_space(1))) void GVoid;
typedef __attribute__((address_space(3))) void LVoid;

#define WAITVM(N) do { asm volatile("s_waitcnt vmcnt(" #N ")" ::: "memory"); \
                       __builtin_amdgcn_sched_barrier(0); } while (0)

// ---- Pre-pass: value fp32 -> fp16 into workspace (halves gather traffic) ----
__global__ __launch_bounds__(256) void cvt_kernel(const float* __restrict__ v,
                                                  uint4* __restrict__ o, int n8) {
    int i = blockIdx.x * blockDim.x + threadIdx.x;
    const float4* __restrict__ v4 = (const float4*)v;
    for (; i < n8; i += gridDim.x * blockDim.x) {
        const float4 f0 = v4[2 * i];
        const float4 f1 = v4[2 * i + 1];
        __half2 h0 = __floats2half2_rn(f0.x, f0.y);
        __half2 h1 = __floats2half2_rn(f0.z, f0.w);
        __half2 h2 = __floats2half2_rn(f1.x, f1.y);
        __half2 h3 = __floats2half2_rn(f1.z, f1.w);
        uint4 u;
        u.x = *reinterpret_cast<unsigned*>(&h0);
        u.y = *reinterpret_cast<unsigned*>(&h1);
        u.z = *reinterpret_cast<unsigned*>(&h2);
        u.w = *reinterpret_cast<unsigned*>(&h3);
        o[i] = u;
    }
}

// Partition (R5 winner): 8 groups = (batch, h-half) -> one per XCD; per-XCD
// gather footprint 3.93 MB fp16 (~L2-capacity-bounded: deep issue can't thrash).
// Block = 8 queries x 4 heads.  Phase 1: 1024 packed descriptors into LDS.
// Phase 2: gather via async global->LDS DMA (global_load_lds, no VGPR data),
// 4-slot wave-private rolling buffer, counted vmcnt(3) -- register-pipeline
// attempts R3/R4/R6/R8 all spilled; DMA staging sidesteps VGPRs entirely.
template <bool FP16>
__global__ __launch_bounds__(256, 6) void spd_kernel(
    const float* __restrict__ value,   // (bs, NK, H, D) fp32
    const __half* __restrict__ vh,     // same, fp16 (workspace), if FP16
    const float* __restrict__ loc,     // (bs, NQ, H, LV, P, 1)
    const float* __restrict__ wts,     // (bs, NQ, H, LV, P)
    float* __restrict__ out)           // (bs, NQ, H*D)
{
    const int tid = threadIdx.x;
    const int g8 = blockIdx.x & 7;     // XCD id = group = b*2 + hh
    const int w  = blockIdx.x >> 3;    // [0,512) within group
    const int b  = g8 >> 1;
    const int hh = g8 & 1;             // which half of the 8 heads
    const int q0 = w << 3;             // first of 8 queries

    __shared__ uint2 s_d[32 * LDSS];                    // descriptors
    __shared__ __align__(16) unsigned char s_stage[4 * 4 * 1024]; // [slot][wave][1KB]

    // ---- Phase 1: descriptors for 8 queries x 4 heads x 32 taps ----
    const size_t base = ((size_t)(b * NQ + q0) * 8 + hh * 4) * 32;
    #pragma unroll
    for (int e = 0; e < 4; ++e) {
        const int ent = (e << 8) | tid;    // q(3b)|h4(2b)|l(2b)|p(3b)
        const size_t gidx = base + (size_t)(ent >> 7) * 256 + (ent & 127);
        const float x_loc = loc[gidx];
        const float wq    = wts[gidx];

        const int l   = (ent >> 3) & 3;
        const int L   = 16384 >> l;
        const int off = 32768 - (32768 >> l); // 0,16384,24576,28672

        const float x  = x_loc * (float)L - 1.0f;
        const float xf = floorf(x);
        const float lx = x - xf;
        const float hx = 1.0f - lx;
        const int   xl = (int)xf;
        const int   xh = xl + 1;

        const bool ok1 = (xl >= 0) && (xl < L);
        const bool ok2 = (xh >= 0) && (xh < L);
        int c1 = xl < 0 ? 0 : (xl > L - 1 ? L - 1 : xl);
        int c2 = xh < 0 ? 0 : (xh > L - 1 ? L - 1 : xh);
        const float w1 = ok1 ? wq * hx : 0.0f;
        const float w2 = ok2 ? wq * lx : 0.0f;

        const int li = (ent & 31) * LDSS + (ent >> 5);  // row=lp, col=q*4+h4
        __half2 wh = __floats2half2_rn(w1, w2);
        uint2 d;
        d.x = (unsigned)(off + c1) | ((unsigned)(off + c2) << 16);
        d.y = *reinterpret_cast<unsigned*>(&wh);
        s_d[li] = d;
    }
    __syncthreads();

    // ---- Phase 2 ----
    const int wave = tid >> 6;
    const int lane = tid & 63;
    const int cb   = tid >> 3;                // LDS col = q*4+h4 [0,32)
    const int gc   = cb & 7;                  // within-wave group
    const int d4   = tid & 7;
    const int h    = (hh << 2) | (cb & 3);
    const unsigned olane = (unsigned)((h << 3) | d4);

    float4 acc = make_float4(0.f, 0.f, 0.f, 0.f);

    if (FP16) {
        const unsigned char* __restrict__ vb =
            (const unsigned char*)vh + (size_t)b * ((size_t)NK * 512); // 512 B/key

        // staging decode: lane l stages 16B granule (sg, k=sf>>2, qt=sf&3),
        // where sf = (l&7)^sg  -> slot l holds swizzled content (consumer
        // reads land 4-way instead of 8-way on banks).
        const int sg  = lane >> 3;
        const int sf  = (lane & 7) ^ sg;
        const int sk  = sf >> 2;
        const int sqt = sf & 3;
        const int sh  = (hh << 2) | (sg & 3);
        const int scol = (wave << 3) + sg;
        const int gq   = (sh << 6) + (sqt << 4);   // within-row byte offset
        unsigned char* const wbase = s_stage + wave * 1024;

        #define STAGE(J) do {                                                 \
            const uint2 dsc_ = s_d[(J) * LDSS + scol];                        \
            const unsigned key_ = sk ? (dsc_.x >> 16) : (dsc_.x & 0xffffu);   \
            const unsigned char* gp_ = vb + ((size_t)key_ << 9) + gq;         \
            __builtin_amdgcn_global_load_lds((GVoid*)gp_,                     \
                (LVoid*)(wbase + (((J) & 3) << 12)), 16, 0, 0);               \
        } while (0)

        #define CONSUME(J) do {                                               \
            const uint2 dsc_ = s_d[(J) * LDSS + cb];                          \
            const __half2 wh_ = *reinterpret_cast<const __half2*>(&dsc_.y);   \
            const float w1_ = __low2float(wh_);                               \
            const float w2_ = __high2float(wh_);                              \
            const unsigned char* sb_ = wbase + (((J) & 3) << 12);             \
            const int f1_ = d4 >> 1;                                          \
            const uint2 r1 = *(const uint2*)(sb_ +                            \
                (((gc << 3) | (f1_ ^ gc)) << 4) + ((d4 & 1) << 3));           \
            const uint2 r2 = *(const uint2*)(sb_ +                            \
                (((gc << 3) | ((4 | f1_) ^ gc)) << 4) + ((d4 & 1) << 3));     \
            const float2 a0 = __half22float2(*(const __half2*)&r1.x);         \
            const float2 a1 = __half22float2(*(const __half2*)&r1.y);         \
            const float2 c0 = __half22float2(*(const __half2*)&r2.x);         \
            const float2 c1 = __half22float2(*(const __half2*)&r2.y);         \
            acc.x += w1_ * a0.x + w2_ * c0.x;                                 \
            acc.y += w1_ * a0.y + w2_ * c0.y;                                 \
            acc.z += w1_ * a1.x + w2_ * c1.x;                                 \
            acc.w += w1_ * a1.y + w2_ * c1.y;                                 \
        } while (0)

        STAGE(0); STAGE(1); STAGE(2);
        for (int j = 0; j < 29; ++j) {
            STAGE(j + 3);
            WAITVM(3);
            CONSUME(j);
        }
        WAITVM(2); CONSUME(29);
        WAITVM(1); CONSUME(30);
        WAITVM(0); CONSUME(31);

        #undef STAGE
        #undef CONSUME
    } else {
        const float4* __restrict__ vb4 =
            (const float4*)(value) + (size_t)b * (NK * 64); // 64 float4 per key
        #pragma unroll 16
        for (int j = 0; j < 32; ++j) {
            const uint2 d = s_d[j * LDSS + cb];
            const __half2 wh = *reinterpret_cast<const __half2*>(&d.y);
            const float w1 = __low2float(wh);
            const float w2 = __high2float(wh);
            const float4 a = vb4[(size_t)((d.x & 0xffffu) << 6) + olane];
            const float4 c = vb4[(size_t)((d.x >> 16) << 6) + olane];
            acc.x += w1 * a.x + w2 * c.x;
            acc.y += w1 * a.y + w2 * c.y;
            acc.z += w1 * a.z + w2 * c.z;
            acc.w += w1 * a.w + w2 * c.w;
        }
    }

    float4* __restrict__ o4 = (float4*)out;
    o4[(size_t)(b * NQ + q0 + (tid >> 5)) * 64 + olane] = acc;
}

extern "C" void kernel_launch(void* const* d_in, const int* in_sizes, int n_in,
                              void* d_out, int out_size, void* d_ws, size_t ws_size,
                              hipStream_t stream) {
    const float* value = (const float*)d_in[0];
    const float* loc   = (const float*)d_in[1];
    const float* wts   = (const float*)d_in[2];
    float* out = (float*)d_out;

    const int bs = 4;
    const int blocks = 8 * (NQ / 8);  // 8 groups x 512 = 4096
    const size_t need = (size_t)bs * NK * NH * ND * sizeof(__half);  // ~63 MB

    if (ws_size >= need) {
        const int n8 = bs * NK * NH * ND / 8;  // 8 floats per thread-iter
        cvt_kernel<<<2048, 256, 0, stream>>>(value, (uint4*)d_ws, n8);
        spd_kernel<true><<<blocks, 256, 0, stream>>>(value, (const __half*)d_ws,
                                                     loc, wts, out);
    } else {
        spd_kernel<false><<<blocks, 256, 0, stream>>>(value, nullptr,
                                                      loc, wts, out);
    }
}